// Round 1
// baseline (606.374 us; speedup 1.0000x reference)
//
#include <hip/hip_runtime.h>
#include <math.h>

typedef __bf16 bf16_t;
typedef __bf16 bf16x2 __attribute__((ext_vector_type(2)));
typedef __bf16 bf16x4 __attribute__((ext_vector_type(4)));
typedef __bf16 bf16x8 __attribute__((ext_vector_type(8)));
typedef float  f32x4  __attribute__((ext_vector_type(4)));

#define D_MODEL 1024
#define T_SEQ   2048
#define BATCH   2
#define NHEAD   16
#define DHEAD   64
#define DFF     4096
#define ROWS    (BATCH * T_SEQ)   // 4096

// ---------------- helpers ----------------
static __device__ __forceinline__ void gload_lds16(const void* g, void* l) {
  __builtin_amdgcn_global_load_lds((const __attribute__((address_space(1))) void*)g,
                                   (__attribute__((address_space(3))) void*)l,
                                   16, 0, 0);
}

// ---------------- f32 -> bf16 convert ----------------
__global__ __launch_bounds__(256) void cvt_bf16_kernel(const float* __restrict__ in,
                                                       bf16_t* __restrict__ out, int n) {
  int i = (blockIdx.x * 256 + threadIdx.x) * 4;
  if (i >= n) return;
  float4 v = *(const float4*)(in + i);
  bf16x4 o;
  o[0] = (bf16_t)v.x; o[1] = (bf16_t)v.y; o[2] = (bf16_t)v.z; o[3] = (bf16_t)v.w;
  *(bf16x4*)(out + i) = o;
}

// ---------------- RoPE tables ----------------
__global__ __launch_bounds__(256) void rope_tables_kernel(float* __restrict__ cost,
                                                          float* __restrict__ sint) {
  int i = blockIdx.x * 256 + threadIdx.x;      // T_SEQ*32
  int t = i >> 5, p = i & 31;
  double inv = pow(10000.0, -(double)(2 * p) / 64.0);
  double ang = (double)t * inv;
  cost[i] = (float)cos(ang);
  sint[i] = (float)sin(ang);
}

// ---------------- RMSNorm (f32 in, bf16 out) ----------------
__global__ __launch_bounds__(256) void rmsnorm_kernel(const float* __restrict__ x,
                                                      const float* __restrict__ g,
                                                      bf16_t* __restrict__ out) {
  const int row = blockIdx.x;
  const int tid = threadIdx.x;          // 256 threads * 4 floats = 1024
  const float4 v = ((const float4*)(x + (size_t)row * D_MODEL))[tid];
  float ss = v.x * v.x + v.y * v.y + v.z * v.z + v.w * v.w;
#pragma unroll
  for (int m = 32; m >= 1; m >>= 1) ss += __shfl_xor(ss, m);
  __shared__ float red[4];
  if ((tid & 63) == 0) red[tid >> 6] = ss;
  __syncthreads();
  float tot = red[0] + red[1] + red[2] + red[3];
  const float rinv = 1.0f / sqrtf(tot * (1.0f / D_MODEL) + 1e-5f);
  const float4 gv = ((const float4*)g)[tid];
  bf16x4 o;
  o[0] = (bf16_t)(v.x * rinv * gv.x);
  o[1] = (bf16_t)(v.y * rinv * gv.y);
  o[2] = (bf16_t)(v.z * rinv * gv.z);
  o[3] = (bf16_t)(v.w * rinv * gv.w);
  *(bf16x4*)(out + (size_t)row * D_MODEL + tid * 4) = o;
}

// ---------------- RoPE apply + scatter qkv -> Q,K,V [B,H,T,dh] ----------------
__global__ __launch_bounds__(256) void rope_scatter_kernel(const bf16_t* __restrict__ qkv,
                                                           const float* __restrict__ cost,
                                                           const float* __restrict__ sint,
                                                           bf16_t* __restrict__ Q,
                                                           bf16_t* __restrict__ K,
                                                           bf16_t* __restrict__ V) {
  int i = blockIdx.x * 256 + threadIdx.x;  // B*T*H*32 = 2^21
  int p = i & 31;
  int h = (i >> 5) & 15;
  int t = (i >> 9) & 2047;
  int b = i >> 20;
  const bf16_t* base = qkv + (size_t)(b * T_SEQ + t) * (3 * D_MODEL) + h * DHEAD + 2 * p;
  float qe = (float)base[0],            qo = (float)base[1];
  float ke = (float)base[D_MODEL],      ko = (float)base[D_MODEL + 1];
  float ve = (float)base[2 * D_MODEL],  vo = (float)base[2 * D_MODEL + 1];
  float c = cost[t * 32 + p], s = sint[t * 32 + p];
  size_t o = ((size_t)(b * NHEAD + h) * T_SEQ + t) * DHEAD + 2 * p;
  bf16x2 qv, kv, vv;
  qv[0] = (bf16_t)(qe * c - qo * s); qv[1] = (bf16_t)(qe * s + qo * c);
  kv[0] = (bf16_t)(ke * c - ko * s); kv[1] = (bf16_t)(ke * s + ko * c);
  vv[0] = (bf16_t)ve;                vv[1] = (bf16_t)vo;
  *(bf16x2*)(Q + o) = qv;
  *(bf16x2*)(K + o) = kv;
  *(bf16x2*)(V + o) = vv;
}

// ---------------- GEMM: C[M,N] = A[M,K] * B[N,K]^T  (+ res, f32 out) ----------------
// EPI=0: store bf16 C.  EPI=1: store f32 C = acc + res.
template <int EPI>
__global__ __launch_bounds__(256) void gemm_bt(const bf16_t* __restrict__ A,
                                               const bf16_t* __restrict__ B,
                                               void* __restrict__ Cout,
                                               const float* __restrict__ res,
                                               int M, int N, int K) {
  __shared__ __align__(16) bf16_t lA[128 * 32];
  __shared__ __align__(16) bf16_t lB[128 * 32];
  const int tid = threadIdx.x;
  const int wave = tid >> 6, lane = tid & 63;
  const int lr = lane & 15, lg = lane >> 4;
  const int brow = blockIdx.y * 128, bcol = blockIdx.x * 128;
  const int wr = (wave >> 1) * 64, wc = (wave & 1) * 64;
  f32x4 acc[4][4] = {};
  for (int k0 = 0; k0 < K; k0 += 32) {
    __syncthreads();  // protect LDS from previous iteration's readers
#pragma unroll
    for (int r = 0; r < 2; ++r) {
      const int base = (r * 4 + wave) * 1024;        // byte offset into 8KB tile
      const int fb = base + lane * 16;               // this lane's byte
      const int row = fb >> 6;                       // 64B per row (32 bf16)
      const int ke = (fb & 63) >> 1;                 // element offset in k
      gload_lds16(A + (size_t)(brow + row) * K + k0 + ke, (char*)lA + base);
      gload_lds16(B + (size_t)(bcol + row) * K + k0 + ke, (char*)lB + base);
    }
    __syncthreads();  // staging complete (vmcnt drained by barrier)
    bf16x8 aF[4], bF[4];
#pragma unroll
    for (int mi = 0; mi < 4; ++mi)
      aF[mi] = *(const bf16x8*)&lA[(wr + mi * 16 + lr) * 32 + 8 * lg];
#pragma unroll
    for (int ni = 0; ni < 4; ++ni)
      bF[ni] = *(const bf16x8*)&lB[(wc + ni * 16 + lr) * 32 + 8 * lg];
#pragma unroll
    for (int mi = 0; mi < 4; ++mi)
#pragma unroll
      for (int ni = 0; ni < 4; ++ni)
        acc[mi][ni] = __builtin_amdgcn_mfma_f32_16x16x32_bf16(aF[mi], bF[ni], acc[mi][ni], 0, 0, 0);
  }
  // epilogue: C/D layout col=lane&15, row=(lane>>4)*4+i
  const int rb = brow + wr + lg * 4;
  const int cb = bcol + wc + lr;
  if (EPI == 0) {
    bf16_t* C = (bf16_t*)Cout;
#pragma unroll
    for (int mi = 0; mi < 4; ++mi)
#pragma unroll
      for (int ni = 0; ni < 4; ++ni)
#pragma unroll
        for (int i = 0; i < 4; ++i)
          C[(size_t)(rb + mi * 16 + i) * N + cb + ni * 16] = (bf16_t)acc[mi][ni][i];
  } else {
    float* C = (float*)Cout;
#pragma unroll
    for (int mi = 0; mi < 4; ++mi)
#pragma unroll
      for (int ni = 0; ni < 4; ++ni)
#pragma unroll
        for (int i = 0; i < 4; ++i) {
          size_t idx = (size_t)(rb + mi * 16 + i) * N + cb + ni * 16;
          C[idx] = acc[mi][ni][i] + res[idx];
        }
  }
}

// ---------------- causal flash attention ----------------
// Q,K,V: [B*H, T, 64] bf16. attn out: [B*T, 1024] bf16.
// block = 4 waves; wave handles 16 q rows; kv blocks of 32; per-wave LDS P tile.
__global__ __launch_bounds__(256) void attn_kernel(const bf16_t* __restrict__ Q,
                                                   const bf16_t* __restrict__ K,
                                                   const bf16_t* __restrict__ V,
                                                   bf16_t* __restrict__ attn) {
  __shared__ __align__(16) bf16_t pbuf[4][16 * 32];
  const int tid = threadIdx.x;
  const int wave = tid >> 6, lane = tid & 63;
  const int lr = lane & 15, lg = lane >> 4;
  const int bh = blockIdx.y;
  const int q0 = blockIdx.x * 64 + wave * 16;
  const size_t hb = (size_t)bh * T_SEQ * DHEAD;
  const bf16_t* Qb = Q + hb;
  const bf16_t* Kb = K + hb;
  const bf16_t* Vb = V + hb;
  bf16x8 qf0 = *(const bf16x8*)&Qb[(q0 + lr) * DHEAD + 8 * lg];
  bf16x8 qf1 = *(const bf16x8*)&Qb[(q0 + lr) * DHEAD + 32 + 8 * lg];
  f32x4 o[4] = {};
  float m[4] = {-INFINITY, -INFINITY, -INFINITY, -INFINITY};
  float lsum[4] = {};
  bf16_t* pw = pbuf[wave];
  const int nb = (q0 + 47) >> 5;   // kv blocks of 32 covering keys <= q0+15
  for (int kb = 0; kb < nb; ++kb) {
    const int k0 = kb * 32;
    f32x4 s[2] = {};
#pragma unroll
    for (int c = 0; c < 2; ++c) {
      const bf16_t* kp = &Kb[(k0 + c * 16 + lr) * DHEAD + 8 * lg];
      bf16x8 kf0 = *(const bf16x8*)kp;
      bf16x8 kf1 = *(const bf16x8*)(kp + 32);
      s[c] = __builtin_amdgcn_mfma_f32_16x16x32_bf16(qf0, kf0, s[c], 0, 0, 0);
      s[c] = __builtin_amdgcn_mfma_f32_16x16x32_bf16(qf1, kf1, s[c], 0, 0, 0);
    }
    const bool need_mask = (k0 + 31 > q0);
#pragma unroll
    for (int c = 0; c < 2; ++c)
#pragma unroll
      for (int i = 0; i < 4; ++i) {
        float v = s[c][i] * 0.125f;
        if (need_mask && (k0 + c * 16 + lr > q0 + lg * 4 + i)) v = -INFINITY;
        s[c][i] = v;
      }
    // block row-max (rows live in 16-lane groups; xor masks 1..8 stay in group)
    float bm[4], al[4];
#pragma unroll
    for (int i = 0; i < 4; ++i) bm[i] = fmaxf(s[0][i], s[1][i]);
#pragma unroll
    for (int xm = 1; xm < 16; xm <<= 1)
#pragma unroll
      for (int i = 0; i < 4; ++i) bm[i] = fmaxf(bm[i], __shfl_xor(bm[i], xm));
#pragma unroll
    for (int i = 0; i < 4; ++i) {
      float mn = fmaxf(m[i], bm[i]);
      al[i] = __expf(m[i] - mn);       // exp(-inf)=0 on first block
      m[i] = mn;
    }
#pragma unroll
    for (int c = 0; c < 2; ++c)
#pragma unroll
      for (int i = 0; i < 4; ++i) s[c][i] = __expf(s[c][i] - m[i]);
    float bs[4];
#pragma unroll
    for (int i = 0; i < 4; ++i) bs[i] = s[0][i] + s[1][i];
#pragma unroll
    for (int xm = 1; xm < 16; xm <<= 1)
#pragma unroll
      for (int i = 0; i < 4; ++i) bs[i] += __shfl_xor(bs[i], xm);
#pragma unroll
    for (int i = 0; i < 4; ++i) lsum[i] = lsum[i] * al[i] + bs[i];
#pragma unroll
    for (int d = 0; d < 4; ++d)
#pragma unroll
      for (int i = 0; i < 4; ++i) o[d][i] *= al[i];
    // P (C-layout) -> LDS -> A-layout fragment
#pragma unroll
    for (int c = 0; c < 2; ++c)
#pragma unroll
      for (int i = 0; i < 4; ++i)
        pw[(lg * 4 + i) * 32 + c * 16 + lr] = (bf16_t)s[c][i];
    asm volatile("s_waitcnt lgkmcnt(0)" ::: "memory");
    __builtin_amdgcn_sched_barrier(0);
    bf16x8 pf = *(const bf16x8*)&pw[lr * 32 + 8 * lg];
#pragma unroll
    for (int d = 0; d < 4; ++d) {
      bf16x8 vf;
#pragma unroll
      for (int j = 0; j < 8; ++j)
        vf[j] = Vb[(size_t)(k0 + 8 * lg + j) * DHEAD + d * 16 + lr];
      o[d] = __builtin_amdgcn_mfma_f32_16x16x32_bf16(pf, vf, o[d], 0, 0, 0);
    }
  }
  const int b = bh >> 4, hh = bh & 15;
#pragma unroll
  for (int d = 0; d < 4; ++d)
#pragma unroll
    for (int i = 0; i < 4; ++i) {
      float val = o[d][i] / lsum[i];
      attn[((size_t)(b * T_SEQ) + q0 + lg * 4 + i) * D_MODEL + hh * DHEAD + d * 16 + lr] =
          (bf16_t)val;
    }
}

// ---------------- SwiGLU elementwise: a = silu(a) * b ----------------
__global__ __launch_bounds__(256) void swiglu_kernel(bf16_t* __restrict__ a,
                                                     const bf16_t* __restrict__ b) {
  size_t i = ((size_t)blockIdx.x * 256 + threadIdx.x) * 8;
  bf16x8 va = *(const bf16x8*)(a + i);
  bf16x8 vb = *(const bf16x8*)(b + i);
  bf16x8 og;
#pragma unroll
  for (int j = 0; j < 8; ++j) {
    float av = (float)va[j];
    float bv = (float)vb[j];
    float gv = av / (1.0f + __expf(-av)) * bv;
    og[j] = (bf16_t)gv;
  }
  *(bf16x8*)(a + i) = og;
}

// ---------------- launch ----------------
extern "C" void kernel_launch(void* const* d_in, const int* in_sizes, int n_in,
                              void* d_out, int out_size, void* d_ws, size_t ws_size,
                              hipStream_t stream) {
  const float* x    = (const float*)d_in[0];
  const float* Wqkv = (const float*)d_in[1];
  const float* Wo   = (const float*)d_in[2];
  const float* g1   = (const float*)d_in[3];
  const float* g2   = (const float*)d_in[4];
  const float* W1   = (const float*)d_in[5];
  const float* W2   = (const float*)d_in[6];
  const float* W3   = (const float*)d_in[7];
  float* out = (float*)d_out;
  char* ws = (char*)d_ws;
  const size_t MB = 1024 * 1024;

  // workspace map (regions overlapped by liveness):
  float*  x1   = (float*)(ws + 0);          // [0,16M)  f32 residual-1 output
  bf16_t* h    = (bf16_t*)(ws + 16 * MB);   // [16,24M) rmsnorm1 out
  bf16_t* attn = (bf16_t*)(ws + 16 * MB);   // reuse (h dead after QKV gemm)
  bf16_t* h2   = (bf16_t*)(ws + 16 * MB);   // reuse (attn dead after Wo gemm)
  bf16_t* qkv  = (bf16_t*)(ws + 24 * MB);   // [24,48M)
  bf16_t* Qb   = (bf16_t*)(ws + 48 * MB);   // [48,56M)
  bf16_t* Kb   = (bf16_t*)(ws + 56 * MB);   // [56,64M)
  bf16_t* Vb   = (bf16_t*)(ws + 64 * MB);   // [64,72M)
  bf16_t* abuf = (bf16_t*)(ws + 24 * MB);   // [24,56M) reuse (qkv,Q dead)
  bf16_t* bbuf = (bf16_t*)(ws + 56 * MB);   // [56,88M) reuse (K,V dead)
  float*  cost = (float*)(ws + 88 * MB);
  float*  sint = (float*)(ws + 88 * MB + 262144);
  bf16_t* wq_b = (bf16_t*)(ws + 89 * MB);   // 6M
  bf16_t* wo_b = (bf16_t*)(ws + 95 * MB);   // 2M
  bf16_t* w1_b = (bf16_t*)(ws + 97 * MB);   // 8M
  bf16_t* w3_b = (bf16_t*)(ws + 105 * MB);  // 8M
  bf16_t* w2_b = (bf16_t*)(ws + 113 * MB);  // 8M  -> peak 121M

  // weight conversion
  cvt_bf16_kernel<<<3 * D_MODEL * D_MODEL / 1024, 256, 0, stream>>>(Wqkv, wq_b, 3 * D_MODEL * D_MODEL);
  cvt_bf16_kernel<<<D_MODEL * D_MODEL / 1024, 256, 0, stream>>>(Wo, wo_b, D_MODEL * D_MODEL);
  cvt_bf16_kernel<<<DFF * D_MODEL / 1024, 256, 0, stream>>>(W1, w1_b, DFF * D_MODEL);
  cvt_bf16_kernel<<<DFF * D_MODEL / 1024, 256, 0, stream>>>(W3, w3_b, DFF * D_MODEL);
  cvt_bf16_kernel<<<DFF * D_MODEL / 1024, 256, 0, stream>>>(W2, w2_b, DFF * D_MODEL);
  rope_tables_kernel<<<(T_SEQ * 32) / 256, 256, 0, stream>>>(cost, sint);

  // attention sub-block
  rmsnorm_kernel<<<ROWS, 256, 0, stream>>>(x, g1, h);
  gemm_bt<0><<<dim3(3 * D_MODEL / 128, ROWS / 128), 256, 0, stream>>>(
      h, wq_b, qkv, nullptr, ROWS, 3 * D_MODEL, D_MODEL);
  rope_scatter_kernel<<<(BATCH * T_SEQ * NHEAD * 32) / 256, 256, 0, stream>>>(
      qkv, cost, sint, Qb, Kb, Vb);
  attn_kernel<<<dim3(T_SEQ / 64, BATCH * NHEAD), 256, 0, stream>>>(Qb, Kb, Vb, attn);
  gemm_bt<1><<<dim3(D_MODEL / 128, ROWS / 128), 256, 0, stream>>>(
      attn, wo_b, x1, x, ROWS, D_MODEL, D_MODEL);

  // FFN sub-block
  rmsnorm_kernel<<<ROWS, 256, 0, stream>>>(x1, g2, h2);
  gemm_bt<0><<<dim3(DFF / 128, ROWS / 128), 256, 0, stream>>>(
      h2, w1_b, abuf, nullptr, ROWS, DFF, D_MODEL);
  gemm_bt<0><<<dim3(DFF / 128, ROWS / 128), 256, 0, stream>>>(
      h2, w3_b, bbuf, nullptr, ROWS, DFF, D_MODEL);
  swiglu_kernel<<<(ROWS * DFF) / (256 * 8), 256, 0, stream>>>(abuf, bbuf);
  gemm_bt<1><<<dim3(D_MODEL / 128, ROWS / 128), 256, 0, stream>>>(
      abuf, w2_b, out, x1, ROWS, D_MODEL, DFF);
}

// Round 2
// 555.383 us; speedup vs baseline: 1.0918x; 1.0918x over previous
//
#include <hip/hip_runtime.h>
#include <math.h>

typedef __bf16 bf16_t;
typedef __bf16 bf16x2 __attribute__((ext_vector_type(2)));
typedef __bf16 bf16x4 __attribute__((ext_vector_type(4)));
typedef __bf16 bf16x8 __attribute__((ext_vector_type(8)));
typedef float  f32x4  __attribute__((ext_vector_type(4)));

#define D_MODEL 1024
#define T_SEQ   2048
#define BATCH   2
#define NHEAD   16
#define DHEAD   64
#define DFF     4096
#define ROWS    (BATCH * T_SEQ)   // 4096

// ---------------- helpers ----------------
static __device__ __forceinline__ void gload_lds16(const void* g, void* l) {
  __builtin_amdgcn_global_load_lds((const __attribute__((address_space(1))) void*)g,
                                   (__attribute__((address_space(3))) void*)l,
                                   16, 0, 0);
}

// ---------------- f32 -> bf16 convert ----------------
__global__ __launch_bounds__(256) void cvt_bf16_kernel(const float* __restrict__ in,
                                                       bf16_t* __restrict__ out, int n) {
  int i = (blockIdx.x * 256 + threadIdx.x) * 4;
  if (i >= n) return;
  float4 v = *(const float4*)(in + i);
  bf16x4 o;
  o[0] = (bf16_t)v.x; o[1] = (bf16_t)v.y; o[2] = (bf16_t)v.z; o[3] = (bf16_t)v.w;
  *(bf16x4*)(out + i) = o;
}

// ---------------- RoPE tables ----------------
__global__ __launch_bounds__(256) void rope_tables_kernel(float* __restrict__ cost,
                                                          float* __restrict__ sint) {
  int i = blockIdx.x * 256 + threadIdx.x;      // T_SEQ*32
  int t = i >> 5, p = i & 31;
  double inv = pow(10000.0, -(double)(2 * p) / 64.0);
  double ang = (double)t * inv;
  cost[i] = (float)cos(ang);
  sint[i] = (float)sin(ang);
}

// ---------------- RMSNorm (f32 in, bf16 out) ----------------
__global__ __launch_bounds__(256) void rmsnorm_kernel(const float* __restrict__ x,
                                                      const float* __restrict__ g,
                                                      bf16_t* __restrict__ out) {
  const int row = blockIdx.x;
  const int tid = threadIdx.x;          // 256 threads * 4 floats = 1024
  const float4 v = ((const float4*)(x + (size_t)row * D_MODEL))[tid];
  float ss = v.x * v.x + v.y * v.y + v.z * v.z + v.w * v.w;
#pragma unroll
  for (int m = 32; m >= 1; m >>= 1) ss += __shfl_xor(ss, m);
  __shared__ float red[4];
  if ((tid & 63) == 0) red[tid >> 6] = ss;
  __syncthreads();
  float tot = red[0] + red[1] + red[2] + red[3];
  const float rinv = 1.0f / sqrtf(tot * (1.0f / D_MODEL) + 1e-5f);
  const float4 gv = ((const float4*)g)[tid];
  bf16x4 o;
  o[0] = (bf16_t)(v.x * rinv * gv.x);
  o[1] = (bf16_t)(v.y * rinv * gv.y);
  o[2] = (bf16_t)(v.z * rinv * gv.z);
  o[3] = (bf16_t)(v.w * rinv * gv.w);
  *(bf16x4*)(out + (size_t)row * D_MODEL + tid * 4) = o;
}

// ---------------- RoPE apply + scatter qkv -> Q,K [B*H,T,dh] ----------------
__global__ __launch_bounds__(256) void rope_scatter_kernel(const bf16_t* __restrict__ qkv,
                                                           const float* __restrict__ cost,
                                                           const float* __restrict__ sint,
                                                           bf16_t* __restrict__ Q,
                                                           bf16_t* __restrict__ K) {
  int i = blockIdx.x * 256 + threadIdx.x;  // B*T*H*32 = 2^21
  int p = i & 31;
  int h = (i >> 5) & 15;
  int t = (i >> 9) & 2047;
  int b = i >> 20;
  const bf16_t* base = qkv + (size_t)(b * T_SEQ + t) * (3 * D_MODEL) + h * DHEAD + 2 * p;
  float qe = (float)base[0],            qo = (float)base[1];
  float ke = (float)base[D_MODEL],      ko = (float)base[D_MODEL + 1];
  float c = cost[t * 32 + p], s = sint[t * 32 + p];
  size_t o = ((size_t)(b * NHEAD + h) * T_SEQ + t) * DHEAD + 2 * p;
  bf16x2 qv, kv;
  qv[0] = (bf16_t)(qe * c - qo * s); qv[1] = (bf16_t)(qe * s + qo * c);
  kv[0] = (bf16_t)(ke * c - ko * s); kv[1] = (bf16_t)(ke * s + ko * c);
  *(bf16x2*)(Q + o) = qv;
  *(bf16x2*)(K + o) = kv;
}

// ---------------- V transpose: qkv V-part -> Vt[bh][d][t] ----------------
// block: 256 thr, handles (bh, 64-row t-tile). LDS transpose, padded stride.
__global__ __launch_bounds__(256) void vt_kernel(const bf16_t* __restrict__ qkv,
                                                 bf16_t* __restrict__ Vt) {
  __shared__ bf16_t ld[64 * 72];
  const int tid = threadIdx.x;
  const int tt = blockIdx.x;           // 0..31 t-tiles
  const int bh = blockIdx.y;           // 0..31
  const int b = bh >> 4, h = bh & 15;
#pragma unroll
  for (int it = 0; it < 2; ++it) {
    int idx = it * 256 + tid;          // 0..511
    int r = idx >> 3, cc = (idx & 7) * 8;
    bf16x8 v = *(const bf16x8*)&qkv[(size_t)(b * T_SEQ + tt * 64 + r) * (3 * D_MODEL)
                                    + 2 * D_MODEL + h * DHEAD + cc];
    *(bf16x8*)&ld[r * 72 + cc] = v;
  }
  __syncthreads();
#pragma unroll
  for (int it = 0; it < 2; ++it) {
    int idx = it * 256 + tid;
    int d = idx >> 3, t8 = (idx & 7) * 8;
    bf16x8 v;
#pragma unroll
    for (int j = 0; j < 8; ++j) v[j] = ld[(t8 + j) * 72 + d];
    *(bf16x8*)&Vt[((size_t)bh * DHEAD + d) * T_SEQ + tt * 64 + t8] = v;
  }
}

// ---------------- GEMM: C[M,N] = A[M,K] * B[N,K]^T  (+ res, f32 out) ----------------
template <int EPI>
__global__ __launch_bounds__(256) void gemm_bt(const bf16_t* __restrict__ A,
                                               const bf16_t* __restrict__ B,
                                               void* __restrict__ Cout,
                                               const float* __restrict__ res,
                                               int M, int N, int K) {
  __shared__ __align__(16) bf16_t lA[128 * 32];
  __shared__ __align__(16) bf16_t lB[128 * 32];
  const int tid = threadIdx.x;
  const int wave = tid >> 6, lane = tid & 63;
  const int lr = lane & 15, lg = lane >> 4;
  const int brow = blockIdx.y * 128, bcol = blockIdx.x * 128;
  const int wr = (wave >> 1) * 64, wc = (wave & 1) * 64;
  f32x4 acc[4][4] = {};
  for (int k0 = 0; k0 < K; k0 += 32) {
    __syncthreads();
#pragma unroll
    for (int r = 0; r < 2; ++r) {
      const int base = (r * 4 + wave) * 1024;
      const int fb = base + lane * 16;
      const int row = fb >> 6;
      const int ke = (fb & 63) >> 1;
      gload_lds16(A + (size_t)(brow + row) * K + k0 + ke, (char*)lA + base);
      gload_lds16(B + (size_t)(bcol + row) * K + k0 + ke, (char*)lB + base);
    }
    __syncthreads();
    bf16x8 aF[4], bF[4];
#pragma unroll
    for (int mi = 0; mi < 4; ++mi)
      aF[mi] = *(const bf16x8*)&lA[(wr + mi * 16 + lr) * 32 + 8 * lg];
#pragma unroll
    for (int ni = 0; ni < 4; ++ni)
      bF[ni] = *(const bf16x8*)&lB[(wc + ni * 16 + lr) * 32 + 8 * lg];
#pragma unroll
    for (int mi = 0; mi < 4; ++mi)
#pragma unroll
      for (int ni = 0; ni < 4; ++ni)
        acc[mi][ni] = __builtin_amdgcn_mfma_f32_16x16x32_bf16(aF[mi], bF[ni], acc[mi][ni], 0, 0, 0);
  }
  const int rb = brow + wr + lg * 4;
  const int cb = bcol + wc + lr;
  if (EPI == 0) {
    bf16_t* C = (bf16_t*)Cout;
#pragma unroll
    for (int mi = 0; mi < 4; ++mi)
#pragma unroll
      for (int ni = 0; ni < 4; ++ni)
#pragma unroll
        for (int i = 0; i < 4; ++i)
          C[(size_t)(rb + mi * 16 + i) * N + cb + ni * 16] = (bf16_t)acc[mi][ni][i];
  } else {
    float* C = (float*)Cout;
#pragma unroll
    for (int mi = 0; mi < 4; ++mi)
#pragma unroll
      for (int ni = 0; ni < 4; ++ni)
#pragma unroll
        for (int i = 0; i < 4; ++i) {
          size_t idx = (size_t)(rb + mi * 16 + i) * N + cb + ni * 16;
          C[idx] = acc[mi][ni][i] + res[idx];
        }
  }
}

// ---------------- causal flash attention v2 ----------------
// Q,K: [B*H, T, 64] bf16; Vt: [B*H, 64, T] bf16. attn out: [B*T, 1024] bf16.
// Block = 4 waves, handles q-tiles {jt, 31-jt} (load-balanced). Wave = 16 q rows
// per task. KV blocks of 64. P via XOR-swizzled per-wave LDS tile.
__global__ __launch_bounds__(256) void attn_kernel(const bf16_t* __restrict__ Q,
                                                   const bf16_t* __restrict__ K,
                                                   const bf16_t* __restrict__ Vt,
                                                   bf16_t* __restrict__ attn) {
  __shared__ __align__(16) bf16_t pbuf[4][16 * 64];
  const int tid = threadIdx.x;
  const int wave = tid >> 6, lane = tid & 63;
  const int lr = lane & 15, lg = lane >> 4;
  const int bh = blockIdx.y;
  const int b = bh >> 4, hh = bh & 15;
  const size_t hb = (size_t)bh * T_SEQ * DHEAD;
  const bf16_t* Qb = Q + hb;
  const bf16_t* Kb = K + hb;
  const bf16_t* Vb = Vt + hb;          // [64][T]
  bf16_t* pw = pbuf[wave];
  char* pwc = (char*)pw;

#pragma unroll
  for (int task = 0; task < 2; ++task) {
    const int tile = task == 0 ? blockIdx.x : 31 - blockIdx.x;
    const int q0 = tile * 64 + wave * 16;
    bf16x8 qf0 = *(const bf16x8*)&Qb[(q0 + lr) * DHEAD + 8 * lg];
    bf16x8 qf1 = *(const bf16x8*)&Qb[(q0 + lr) * DHEAD + 32 + 8 * lg];
    f32x4 o[4] = {};
    float m[4] = {-INFINITY, -INFINITY, -INFINITY, -INFINITY};
    float lsum[4] = {};
    const int nb = (q0 + 79) >> 6;     // kv blocks of 64 covering keys <= q0+15
    for (int kb = 0; kb < nb; ++kb) {
      const int k0 = kb * 64;
      f32x4 s[4] = {};
#pragma unroll
      for (int c = 0; c < 4; ++c) {
        const bf16_t* kp = &Kb[(k0 + c * 16 + lr) * DHEAD + 8 * lg];
        bf16x8 kf0 = *(const bf16x8*)kp;
        bf16x8 kf1 = *(const bf16x8*)(kp + 32);
        s[c] = __builtin_amdgcn_mfma_f32_16x16x32_bf16(qf0, kf0, s[c], 0, 0, 0);
        s[c] = __builtin_amdgcn_mfma_f32_16x16x32_bf16(qf1, kf1, s[c], 0, 0, 0);
      }
      const bool need_mask = (k0 + 63 > q0);
#pragma unroll
      for (int c = 0; c < 4; ++c)
#pragma unroll
        for (int i = 0; i < 4; ++i) {
          float v = s[c][i] * 0.125f;
          if (need_mask && (k0 + c * 16 + lr > q0 + lg * 4 + i)) v = -INFINITY;
          s[c][i] = v;
        }
      // row max over cols (cols live across c and the 16-lane lr group)
      float bm[4], al[4];
#pragma unroll
      for (int i = 0; i < 4; ++i)
        bm[i] = fmaxf(fmaxf(s[0][i], s[1][i]), fmaxf(s[2][i], s[3][i]));
#pragma unroll
      for (int xm = 1; xm < 16; xm <<= 1)
#pragma unroll
        for (int i = 0; i < 4; ++i) bm[i] = fmaxf(bm[i], __shfl_xor(bm[i], xm));
#pragma unroll
      for (int i = 0; i < 4; ++i) {
        float mn = fmaxf(m[i], bm[i]);
        al[i] = __expf(m[i] - mn);     // exp(-inf)=0 on first block
        m[i] = mn;
      }
#pragma unroll
      for (int c = 0; c < 4; ++c)
#pragma unroll
        for (int i = 0; i < 4; ++i) s[c][i] = __expf(s[c][i] - m[i]);
      float bs[4];
#pragma unroll
      for (int i = 0; i < 4; ++i)
        bs[i] = (s[0][i] + s[1][i]) + (s[2][i] + s[3][i]);
#pragma unroll
      for (int xm = 1; xm < 16; xm <<= 1)
#pragma unroll
        for (int i = 0; i < 4; ++i) bs[i] += __shfl_xor(bs[i], xm);
#pragma unroll
      for (int i = 0; i < 4; ++i) lsum[i] = lsum[i] * al[i] + bs[i];
#pragma unroll
      for (int d = 0; d < 4; ++d)
#pragma unroll
        for (int i = 0; i < 4; ++i) o[d][i] *= al[i];
      // P (C-layout: row=lg*4+i, col=c*16+lr) -> swizzled LDS
#pragma unroll
      for (int c = 0; c < 4; ++c)
#pragma unroll
        for (int i = 0; i < 4; ++i) {
          const int row = lg * 4 + i;
          const int byt = (row * 128 + c * 32 + lr * 2) ^ ((row & 7) << 4);
          *(bf16_t*)(pwc + byt) = (bf16_t)s[c][i];
        }
      asm volatile("s_waitcnt lgkmcnt(0)" ::: "memory");
      __builtin_amdgcn_sched_barrier(0);
      // PV: A = P (rows lr), B = Vt rows (d*16+lr)
      bf16x8 pf[2];
#pragma unroll
      for (int c2 = 0; c2 < 2; ++c2) {
        const int byt = (lr * 128 + c2 * 64 + lg * 16) ^ ((lr & 7) << 4);
        pf[c2] = *(const bf16x8*)(pwc + byt);
      }
#pragma unroll
      for (int d = 0; d < 4; ++d) {
        const bf16_t* vp = &Vb[(size_t)(d * 16 + lr) * T_SEQ + k0 + 8 * lg];
        bf16x8 vf0 = *(const bf16x8*)vp;
        bf16x8 vf1 = *(const bf16x8*)(vp + 32);
        o[d] = __builtin_amdgcn_mfma_f32_16x16x32_bf16(pf[0], vf0, o[d], 0, 0, 0);
        o[d] = __builtin_amdgcn_mfma_f32_16x16x32_bf16(pf[1], vf1, o[d], 0, 0, 0);
      }
    }
#pragma unroll
    for (int d = 0; d < 4; ++d)
#pragma unroll
      for (int i = 0; i < 4; ++i) {
        float val = o[d][i] / lsum[i];
        attn[((size_t)(b * T_SEQ) + q0 + lg * 4 + i) * D_MODEL + hh * DHEAD + d * 16 + lr] =
            (bf16_t)val;
      }
  }
}

// ---------------- SwiGLU elementwise: a = silu(a) * b ----------------
__global__ __launch_bounds__(256) void swiglu_kernel(bf16_t* __restrict__ a,
                                                     const bf16_t* __restrict__ b) {
  size_t i = ((size_t)blockIdx.x * 256 + threadIdx.x) * 8;
  bf16x8 va = *(const bf16x8*)(a + i);
  bf16x8 vb = *(const bf16x8*)(b + i);
  bf16x8 og;
#pragma unroll
  for (int j = 0; j < 8; ++j) {
    float av = (float)va[j];
    float bv = (float)vb[j];
    float gv = av / (1.0f + __expf(-av)) * bv;
    og[j] = (bf16_t)gv;
  }
  *(bf16x8*)(a + i) = og;
}

// ---------------- launch ----------------
extern "C" void kernel_launch(void* const* d_in, const int* in_sizes, int n_in,
                              void* d_out, int out_size, void* d_ws, size_t ws_size,
                              hipStream_t stream) {
  const float* x    = (const float*)d_in[0];
  const float* Wqkv = (const float*)d_in[1];
  const float* Wo   = (const float*)d_in[2];
  const float* g1   = (const float*)d_in[3];
  const float* g2   = (const float*)d_in[4];
  const float* W1   = (const float*)d_in[5];
  const float* W2   = (const float*)d_in[6];
  const float* W3   = (const float*)d_in[7];
  float* out = (float*)d_out;
  char* ws = (char*)d_ws;
  const size_t MB = 1024 * 1024;

  // workspace map (regions overlapped by liveness):
  float*  x1   = (float*)(ws + 0);          // [0,16M)  f32 residual-1 output
  bf16_t* h    = (bf16_t*)(ws + 16 * MB);   // [16,24M) rmsnorm1 out
  bf16_t* attn = (bf16_t*)(ws + 16 * MB);   // reuse (h dead after QKV gemm)
  bf16_t* h2   = (bf16_t*)(ws + 16 * MB);   // reuse (attn dead after Wo gemm)
  bf16_t* qkv  = (bf16_t*)(ws + 24 * MB);   // [24,48M)
  bf16_t* Qb   = (bf16_t*)(ws + 48 * MB);   // [48,56M)
  bf16_t* Kb   = (bf16_t*)(ws + 56 * MB);   // [56,64M)
  bf16_t* Vt   = (bf16_t*)(ws + 64 * MB);   // [64,72M)  V^T [bh][d][t]
  bf16_t* abuf = (bf16_t*)(ws + 24 * MB);   // [24,56M) reuse (qkv,Q dead)
  bf16_t* bbuf = (bf16_t*)(ws + 56 * MB);   // [56,88M) reuse (K,Vt dead)
  float*  cost = (float*)(ws + 88 * MB);
  float*  sint = (float*)(ws + 88 * MB + 262144);
  bf16_t* wq_b = (bf16_t*)(ws + 89 * MB);   // 6M
  bf16_t* wo_b = (bf16_t*)(ws + 95 * MB);   // 2M
  bf16_t* w1_b = (bf16_t*)(ws + 97 * MB);   // 8M
  bf16_t* w3_b = (bf16_t*)(ws + 105 * MB);  // 8M
  bf16_t* w2_b = (bf16_t*)(ws + 113 * MB);  // 8M  -> peak 121M

  // weight conversion
  cvt_bf16_kernel<<<3 * D_MODEL * D_MODEL / 1024, 256, 0, stream>>>(Wqkv, wq_b, 3 * D_MODEL * D_MODEL);
  cvt_bf16_kernel<<<D_MODEL * D_MODEL / 1024, 256, 0, stream>>>(Wo, wo_b, D_MODEL * D_MODEL);
  cvt_bf16_kernel<<<DFF * D_MODEL / 1024, 256, 0, stream>>>(W1, w1_b, DFF * D_MODEL);
  cvt_bf16_kernel<<<DFF * D_MODEL / 1024, 256, 0, stream>>>(W3, w3_b, DFF * D_MODEL);
  cvt_bf16_kernel<<<DFF * D_MODEL / 1024, 256, 0, stream>>>(W2, w2_b, DFF * D_MODEL);
  rope_tables_kernel<<<(T_SEQ * 32) / 256, 256, 0, stream>>>(cost, sint);

  // attention sub-block
  rmsnorm_kernel<<<ROWS, 256, 0, stream>>>(x, g1, h);
  gemm_bt<0><<<dim3(3 * D_MODEL / 128, ROWS / 128), 256, 0, stream>>>(
      h, wq_b, qkv, nullptr, ROWS, 3 * D_MODEL, D_MODEL);
  rope_scatter_kernel<<<(BATCH * T_SEQ * NHEAD * 32) / 256, 256, 0, stream>>>(
      qkv, cost, sint, Qb, Kb);
  vt_kernel<<<dim3(T_SEQ / 64, BATCH * NHEAD), 256, 0, stream>>>(qkv, Vt);
  attn_kernel<<<dim3(T_SEQ / 128, BATCH * NHEAD), 256, 0, stream>>>(Qb, Kb, Vt, attn);
  gemm_bt<1><<<dim3(D_MODEL / 128, ROWS / 128), 256, 0, stream>>>(
      attn, wo_b, x1, x, ROWS, D_MODEL, D_MODEL);

  // FFN sub-block
  rmsnorm_kernel<<<ROWS, 256, 0, stream>>>(x1, g2, h2);
  gemm_bt<0><<<dim3(DFF / 128, ROWS / 128), 256, 0, stream>>>(
      h2, w1_b, abuf, nullptr, ROWS, DFF, D_MODEL);
  gemm_bt<0><<<dim3(DFF / 128, ROWS / 128), 256, 0, stream>>>(
      h2, w3_b, bbuf, nullptr, ROWS, DFF, D_MODEL);
  swiglu_kernel<<<(ROWS * DFF) / (256 * 8), 256, 0, stream>>>(abuf, bbuf);
  gemm_bt<1><<<dim3(D_MODEL / 128, ROWS / 128), 256, 0, stream>>>(
      abuf, w2_b, out, x1, ROWS, D_MODEL, DFF);
}